// Round 8
// baseline (170.667 us; speedup 1.0000x reference)
//
#include <hip/hip_runtime.h>
#include <hip/hip_bf16.h>

#define B_ 8
#define T_ 2048
#define E_ 1024
#define D_ 128

typedef __attribute__((ext_vector_type(8))) short short8;
typedef __attribute__((ext_vector_type(4))) short short4v;
typedef __attribute__((ext_vector_type(4))) float floatx4;
typedef __attribute__((ext_vector_type(16))) float floatx16;

__device__ __forceinline__ unsigned short f2b(float f) {
  union { float f; unsigned int u; } v; v.f = f;
  unsigned int u = v.u;
  return (unsigned short)((u + 0x7fffu + ((u >> 16) & 1u)) >> 16);  // RNE
}

__device__ __forceinline__ short8 cvt8(float4 a, float4 b) {
  union { short8 s; __hip_bfloat162 h[4]; } u;
  u.h[0] = __float22bfloat162_rn(float2{a.x, a.y});
  u.h[1] = __float22bfloat162_rn(float2{a.z, a.w});
  u.h[2] = __float22bfloat162_rn(float2{b.x, b.y});
  u.h[3] = __float22bfloat162_rn(float2{b.z, b.w});
  return u.s;
}

#if defined(__has_builtin)
#if __has_builtin(__builtin_amdgcn_exp2f)
#define EXP2F(x) __builtin_amdgcn_exp2f(x)
#else
#define EXP2F(x) exp2f(x)
#endif
#else
#define EXP2F(x) exp2f(x)
#endif

// ---------------------------------------------------------------------------
// Kernel 1: W [1024x128] fp32 -> Wp B-FRAG-PACKED bf16:
//   Wp[ct = ch/32][kc = k/16][lane = hi*32 + n32][j]  (B: n=l32, k=hi*8+j)
// ct 0..3 = Q (scale folded), 4..7 = K, 8..11 = V. 96 blocks x 256 thr.
// ---------------------------------------------------------------------------
__global__ __launch_bounds__(256) void wtrans_kernel(
    const float* __restrict__ Wq, const float* __restrict__ Wk,
    const float* __restrict__ Wv, unsigned short* __restrict__ Wp) {
  __shared__ __align__(16) unsigned short Tls[32][136];  // [n][k-local]
  const int tid = threadIdx.x;
  const int w = blockIdx.x >> 5;
  const int rem = blockIdx.x & 31;
  const int k0 = (rem >> 2) * 128;
  const int n0 = (rem & 3) * 32;
  const float* W = (w == 0) ? Wq : ((w == 1) ? Wk : Wv);
  const float scale = (w == 0) ? (1.4426950408889634f * 0.08838834764831845f) : 1.0f;
#pragma unroll
  for (int j = 0; j < 4; j++) {
    int id = tid + 256 * j;
    int k = id >> 3;
    int nn = (id & 7) * 4;
    float4 v = *(const float4*)(W + (size_t)(k0 + k) * D_ + n0 + nn);
    Tls[nn + 0][k] = f2b(v.x * scale);
    Tls[nn + 1][k] = f2b(v.y * scale);
    Tls[nn + 2][k] = f2b(v.z * scale);
    Tls[nn + 3][k] = f2b(v.w * scale);
  }
  __syncthreads();
  const int ct = w * 4 + (rem & 3);
  const int kc0 = (rem >> 2) * 8;
#pragma unroll
  for (int jj = 0; jj < 2; jj++) {
    int id = tid + 256 * jj;      // 512 x 16B = 32n x 16(kc,hi)
    int kchi = id >> 5;
    int n = id & 31;
    int kc = kc0 + (kchi >> 1);
    int hi = kchi & 1;
    short8 o = *(const short8*)&Tls[n][kchi * 8];
    *(short8*)&Wp[((size_t)(ct * 64 + kc) * 64 + hi * 32 + n) * 8] = o;
  }
}

// ---------------------------------------------------------------------------
// Kernel 2: QKV GEMM — ZERO LDS, ZERO BARRIERS (r7 attn recipe applied).
// 512 blocks x 256 thr (4 waves); wave = tok-tile (tg*4+wv, 32 tok) x 96 ch
// (cg, 3 acc tiles). 2048 independent waves = 8 waves/CU.
// A-frags: direct fp32 X reads (hi-pair covers a full 64B line, no overfetch)
// + packed cvt. B-frags: 1KB coalesced loads from L2-resident Wp. Ping-pong
// prefetch one k-step ahead. Epilogue writes Qf/Kf/Vf frag-packed (r7 layout):
//   Qf/Kf[b][tile][kf=d/16][lane=((d>>3)&1)*32 + t32][j=d&7]
//   Vf[b][tile][f=k2*4+dt][lane=((t>>3)&1)*32 + d32][j=t&7]
// ---------------------------------------------------------------------------
__global__ __launch_bounds__(256, 2) void qkv_kernel(
    const float* __restrict__ X, const unsigned short* __restrict__ Wp,
    unsigned short* __restrict__ Qf, unsigned short* __restrict__ Kf,
    unsigned short* __restrict__ Vf) {
  const int tid = threadIdx.x;
  const int wv = tid >> 6;
  const int lane = tid & 63;
  const int l32 = lane & 31;
  const int hi = lane >> 5;

  const int cg = blockIdx.x & 3;         // ch-group: ct = cg*3 + c
  const int tg = blockIdx.x >> 2;        // 0..127
  const int tile = tg * 4 + wv;          // 0..511
  const int t0 = tile * 32;

  const float* Xr = X + (size_t)(t0 + l32) * E_ + hi * 8;
  const unsigned short* Wb = Wp + (size_t)cg * 3 * 32768;

  floatx16 acc[3];
#pragma unroll
  for (int c = 0; c < 3; c++)
#pragma unroll
    for (int r = 0; r < 16; r++) acc[c][r] = 0.f;

  float4 x0A, x1A, x0B, x1B;
  short8 bA[3], bB[3];
  x0A = *(const float4*)(Xr);
  x1A = *(const float4*)(Xr + 4);
#pragma unroll
  for (int c = 0; c < 3; c++)
    bA[c] = *(const short8*)(Wb + c * 32768 + lane * 8);

  for (int kc = 0; kc < 64; kc += 2) {
    // prefetch kc+1
    x0B = *(const float4*)(Xr + (kc + 1) * 16);
    x1B = *(const float4*)(Xr + (kc + 1) * 16 + 4);
#pragma unroll
    for (int c = 0; c < 3; c++)
      bB[c] = *(const short8*)(Wb + c * 32768 + (kc + 1) * 512 + lane * 8);
    {
      short8 a = cvt8(x0A, x1A);
#pragma unroll
      for (int c = 0; c < 3; c++)
        acc[c] = __builtin_amdgcn_mfma_f32_32x32x16_bf16(a, bA[c], acc[c], 0, 0, 0);
    }
    // prefetch kc+2
    if (kc + 2 < 64) {
      x0A = *(const float4*)(Xr + (kc + 2) * 16);
      x1A = *(const float4*)(Xr + (kc + 2) * 16 + 4);
#pragma unroll
      for (int c = 0; c < 3; c++)
        bA[c] = *(const short8*)(Wb + c * 32768 + (kc + 2) * 512 + lane * 8);
    }
    {
      short8 a = cvt8(x0B, x1B);
#pragma unroll
      for (int c = 0; c < 3; c++)
        acc[c] = __builtin_amdgcn_mfma_f32_32x32x16_bf16(a, bB[c], acc[c], 0, 0, 0);
    }
  }

  // Epilogue. C/D 32x32: col n = l32, row m(t) = (r&3)+8*(r>>2)+4*hi.
  const int b = tile >> 6;
  const int tb = tile & 63;
#pragma unroll
  for (int c = 0; c < 3; c++) {
    const int ct = cg * 3 + c;
    const int n = ct * 32 + l32;
    if (n < 256) {
      unsigned short* Fg = (n < 128) ? Qf : Kf;
      const int d = n & 127;
      size_t base = ((size_t)((b * 64 + tb) * 8 + (d >> 4))) * 512 +
                    ((d >> 3) & 1) * 256 + (d & 7);
#pragma unroll
      for (int r = 0; r < 16; r++) {
        int t32 = (r & 3) + 8 * (r >> 2) + 4 * hi;
        Fg[base + (size_t)t32 * 8] = f2b(acc[c][r]);
      }
    } else {
      const int d = n - 256;
      const int dt = d >> 5;
      const int d32 = d & 31;
#pragma unroll
      for (int rg = 0; rg < 4; rg++) {
        short4v pv;
        pv.x = (short)f2b(acc[c][rg * 4 + 0]);
        pv.y = (short)f2b(acc[c][rg * 4 + 1]);
        pv.z = (short)f2b(acc[c][rg * 4 + 2]);
        pv.w = (short)f2b(acc[c][rg * 4 + 3]);
        size_t base = ((size_t)((b * 64 + tb) * 8 + (rg >> 1) * 4 + dt)) * 512 +
                      (size_t)((rg & 1) * 32 + d32) * 8 + 4 * hi;
        *(short4v*)&Vf[base] = pv;
      }
    }
  }
}

// ---------------------------------------------------------------------------
// Kernel 3: causal flash attention (r7, unchanged): frag-packed register-
// direct, barrier-free K-loop, manual K ping-pong prefetch, LDS end-merge.
// ---------------------------------------------------------------------------
#define LOADK(DST, ITV)                                                      \
  _Pragma("unroll") for (int kf_ = 0; kf_ < 8; kf_++)                        \
      DST[kf_] = *(const short8*)(Kbase + (size_t)(ITV) * 4096 + kf_ * 512 + lane * 8);

#define LOADV(DST, ITV)                                                      \
  _Pragma("unroll") for (int f_ = 0; f_ < 8; f_++)                           \
      DST[f_] = *(const short8*)(Vbase + (size_t)(ITV) * 4096 + f_ * 512 + lane * 8);

#define ATTN_STEP(KFR, VFR, ITV)                                             \
  {                                                                          \
    floatx16 sacc;                                                           \
    _Pragma("unroll") for (int r = 0; r < 16; r++) sacc[r] = 0.f;            \
    _Pragma("unroll") for (int kf = 0; kf < 8; kf++)                         \
        sacc = __builtin_amdgcn_mfma_f32_32x32x16_bf16(KFR[kf], qf[kf], sacc, 0, 0, 0); \
    if ((ITV) == qt) {                                                       \
      _Pragma("unroll") for (int r = 0; r < 16; r++) {                       \
        int kv = (ITV) * 32 + (r & 3) + 8 * (r >> 2) + 4 * hi;               \
        if (kv > qg) sacc[r] = -1e30f;                                       \
      }                                                                      \
    }                                                                        \
    float mx = -1e30f;                                                       \
    _Pragma("unroll") for (int r = 0; r < 16; r++) mx = fmaxf(mx, sacc[r]);  \
    mx = fmaxf(mx, __shfl_xor(mx, 32, 64));                                  \
    float mnew = fmaxf(mval, mx);                                            \
    float alpha = EXP2F(mval - mnew);                                        \
    mval = mnew;                                                             \
    float ps = 0.f;                                                          \
    _Pragma("unroll") for (int r = 0; r < 16; r++) {                         \
      float p = EXP2F(sacc[r] - mnew);                                       \
      sacc[r] = p;                                                           \
      ps += p;                                                               \
    }                                                                        \
    ps += __shfl_xor(ps, 32, 64);                                            \
    lval = lval * alpha + ps;                                                \
    _Pragma("unroll") for (int dt = 0; dt < 4; dt++)                         \
        _Pragma("unroll") for (int r = 0; r < 16; r++) oacc[dt][r] *= alpha; \
    unsigned int qp[8], xp[8];                                               \
    _Pragma("unroll") for (int i = 0; i < 8; i++)                            \
        qp[i] = (unsigned int)f2b(sacc[2 * i]) |                             \
                ((unsigned int)f2b(sacc[2 * i + 1]) << 16);                  \
    _Pragma("unroll") for (int i = 0; i < 8; i++)                            \
        xp[i] = (unsigned int)__shfl_xor((int)qp[i], 32, 64);                \
    union { short8 s; unsigned int u[4]; } pf0, pf1;                         \
    pf0.u[0] = hi ? xp[2] : qp[0];                                           \
    pf0.u[1] = hi ? xp[3] : qp[1];                                           \
    pf0.u[2] = hi ? qp[2] : xp[0];                                           \
    pf0.u[3] = hi ? qp[3] : xp[1];                                           \
    pf1.u[0] = hi ? xp[6] : qp[4];                                           \
    pf1.u[1] = hi ? xp[7] : qp[5];                                           \
    pf1.u[2] = hi ? qp[6] : xp[4];                                           \
    pf1.u[3] = hi ? qp[7] : xp[5];                                           \
    _Pragma("unroll") for (int dt = 0; dt < 4; dt++) {                       \
      oacc[dt] = __builtin_amdgcn_mfma_f32_32x32x16_bf16(VFR[dt], pf0.s, oacc[dt], 0, 0, 0);     \
      oacc[dt] = __builtin_amdgcn_mfma_f32_32x32x16_bf16(VFR[4 + dt], pf1.s, oacc[dt], 0, 0, 0); \
    }                                                                        \
  }

__global__ __launch_bounds__(256, 2) void attn_kernel(
    const unsigned short* __restrict__ Qf, const unsigned short* __restrict__ Kf,
    const unsigned short* __restrict__ Vf, float* __restrict__ Out) {
  __shared__ float Om[3][128][32];  // 48 KB merge buffer
  __shared__ float Ms[4][32], Ls[4][32];

  const int tid = threadIdx.x;
  const int wv = tid >> 6;
  const int lane = tid & 63;
  const int l32 = lane & 31;
  const int hi = lane >> 5;

  const int batch = blockIdx.x & 7;
  const int qt = 63 - (blockIdx.x >> 3);  // longest-first
  const int qb = qt * 32;
  const int qg = qb + l32;

  const unsigned short* Kbase = Kf + (size_t)batch * 64 * 4096;
  const unsigned short* Vbase = Vf + (size_t)batch * 64 * 4096;

  short8 qf[8];
  const unsigned short* Qp = Qf + (size_t)(batch * 64 + qt) * 4096;
#pragma unroll
  for (int kf = 0; kf < 8; kf++)
    qf[kf] = *(const short8*)(Qp + kf * 512 + lane * 8);

  floatx16 oacc[4];
#pragma unroll
  for (int dt = 0; dt < 4; dt++)
#pragma unroll
    for (int r = 0; r < 16; r++) oacc[dt][r] = 0.f;
  float mval = -1e30f, lval = 0.f;

  short8 kA[8], kB[8], vC[8];
  int it = wv;
  if (it <= qt) {
    LOADK(kA, it);
    while (true) {
      int nit = it + 4;
      LOADV(vC, it);
      if (nit <= qt) LOADK(kB, nit);
      ATTN_STEP(kA, vC, it);
      if (nit > qt) break;
      it = nit;
      nit = it + 4;
      LOADV(vC, it);
      if (nit <= qt) LOADK(kA, nit);
      ATTN_STEP(kB, vC, it);
      if (nit > qt) break;
      it = nit;
    }
  }

  if (wv) {
    if (hi == 0) { Ms[wv][l32] = mval; Ls[wv][l32] = lval; }
#pragma unroll
    for (int dt = 0; dt < 4; dt++)
#pragma unroll
      for (int r = 0; r < 16; r++) {
        int d = dt * 32 + (r & 3) + 8 * (r >> 2) + 4 * hi;
        Om[wv - 1][d][l32] = oacc[dt][r];
      }
  }
  __syncthreads();
  if (wv == 0) {
    float m1 = Ms[1][l32], m2 = Ms[2][l32], m3 = Ms[3][l32];
    float l1 = Ls[1][l32], l2 = Ls[2][l32], l3 = Ls[3][l32];
    float mstar = fmaxf(fmaxf(mval, m1), fmaxf(m2, m3));
    float a0 = EXP2F(mval - mstar);
    float a1 = EXP2F(m1 - mstar);
    float a2 = EXP2F(m2 - mstar);
    float a3 = EXP2F(m3 - mstar);
    float linv = 1.f / (lval * a0 + l1 * a1 + l2 * a2 + l3 * a3);
    float* Og = Out + ((size_t)batch * T_ + qg) * D_;
#pragma unroll
    for (int dt = 0; dt < 4; dt++)
#pragma unroll
      for (int rg = 0; rg < 4; rg++) {
        int dbase = dt * 32 + 8 * rg + 4 * hi;
        float4 o;
#pragma unroll
        for (int c = 0; c < 4; c++) {
          float v = oacc[dt][rg * 4 + c] * a0 +
                    Om[0][dbase + c][l32] * a1 +
                    Om[1][dbase + c][l32] * a2 +
                    Om[2][dbase + c][l32] * a3;
          ((float*)&o)[c] = v * linv;
        }
        *(float4*)&Og[dbase] = o;
      }
  }
}

// ---------------------------------------------------------------------------
extern "C" void kernel_launch(void* const* d_in, const int* in_sizes, int n_in,
                              void* d_out, int out_size, void* d_ws, size_t ws_size,
                              hipStream_t stream) {
  const float* X  = (const float*)d_in[0];
  const float* Wq = (const float*)d_in[1];
  const float* Wk = (const float*)d_in[2];
  const float* Wv = (const float*)d_in[3];
  float* Out = (float*)d_out;

  char* ws = (char*)d_ws;
  unsigned short* Wp  = (unsigned short*)(ws);                        // 768 KB
  unsigned short* Qf  = (unsigned short*)(ws + 786432);               // 4 MB
  unsigned short* Kf  = (unsigned short*)(ws + 786432 + 4194304);     // 4 MB
  unsigned short* Vf  = (unsigned short*)(ws + 786432 + 2 * 4194304); // 4 MB

  hipLaunchKernelGGL(wtrans_kernel, dim3(96), dim3(256), 0, stream, Wq, Wk, Wv, Wp);
  hipLaunchKernelGGL(qkv_kernel, dim3(512), dim3(256), 0, stream, X, Wp, Qf, Kf, Vf);
  hipLaunchKernelGGL(attn_kernel, dim3(512), dim3(256), 0, stream, Qf, Kf, Vf, Out);
}